// Round 4
// baseline (1608.967 us; speedup 1.0000x reference)
//
#include <hip/hip_runtime.h>

#define NN 200000
#define EE 6400000L
#define NCB 196          // coarse buckets of 1024 nodes: 199999>>10 = 195
#define TILE 8192
#define NTILE 782        // ceil(6400000/8192)

// ---------------------------------------------------------------------------
// Edge-index dtype hedge (int64 vs int32): if int64 with values < 2^31, every
// odd 32-bit word is zero. flag=1 -> int64 (word idx = elem<<1), 0 -> int32.
// ---------------------------------------------------------------------------
__global__ void k_detect(const int* __restrict__ w, int* __restrict__ flag) {
    __shared__ int any;
    if (threadIdx.x == 0) any = 0;
    __syncthreads();
    int found = 0;
    for (int i = threadIdx.x; i < 8192; i += 256)
        if (w[2 * i + 1] != 0) found = 1;
    if (found) atomicOr(&any, 1);
    __syncthreads();
    if (threadIdx.x == 0) flag[0] = any ? 0 : 1;
}

// LDS-aggregated histogram of coarse bucket (d>>10)
__global__ __launch_bounds__(256) void k_histA(
    const int* __restrict__ ew, const int* __restrict__ flag,
    int* __restrict__ counts, long e) {
    __shared__ int lh[NCB];
    for (int i = threadIdx.x; i < NCB; i += 256) lh[i] = 0;
    __syncthreads();
    long t0 = (long)blockIdx.x * TILE;
    int cnt = (int)min((long)TILE, e - t0);
    int shift = *flag;
    for (int i = threadIdx.x; i < cnt; i += 256) {
        int d = ew[(EE + t0 + i) << shift];
        atomicAdd(&lh[d >> 10], 1);
    }
    __syncthreads();
    for (int i = threadIdx.x; i < NCB; i += 256)
        if (lh[i]) atomicAdd(&counts[i], lh[i]);
}

// Exclusive scan of counts[NCB] -> gbase[NCB+1]; gcur = gbase
__global__ __launch_bounds__(256) void k_scanA(
    const int* __restrict__ counts, int* __restrict__ gbase, int* __restrict__ gcur) {
    __shared__ int ws[4];
    int t = threadIdx.x;
    int v = (t < NCB) ? counts[t] : 0;
    int lane = t & 63, w = t >> 6;
    int s = v;
#pragma unroll
    for (int o = 1; o < 64; o <<= 1) {
        int u = __shfl_up(s, o, 64);
        if (lane >= o) s += u;
    }
    if (lane == 63) ws[w] = s;
    __syncthreads();
    int add = 0;
    for (int k = 0; k < w; ++k) add += ws[k];
    int excl = s - v + add;
    if (t <= NCB) gbase[t] = excl;   // t==NCB gets the grand total
    if (t < NCB) gcur[t] = excl;
}

// Partition into coarse buckets with tile-exclusive segments.
// stage entry: src[17:0] | local_dst[27:18]
__global__ __launch_bounds__(256) void k_passA(
    const int* __restrict__ ew, const int* __restrict__ flag,
    int* __restrict__ gcur, unsigned* __restrict__ stage, long e) {
    __shared__ unsigned lv[TILE];
    __shared__ unsigned char lb[TILE];
    __shared__ int lh[NCB], lseg[NCB], lcur[NCB];
    for (int i = threadIdx.x; i < NCB; i += 256) { lh[i] = 0; lcur[i] = 0; }
    __syncthreads();
    long t0 = (long)blockIdx.x * TILE;
    int cnt = (int)min((long)TILE, e - t0);
    int shift = *flag;
    for (int i = threadIdx.x; i < cnt; i += 256) {
        int s = ew[(t0 + i) << shift];
        int d = ew[(EE + t0 + i) << shift];
        int b = d >> 10;
        lv[i] = (unsigned)s | ((unsigned)(d & 1023) << 18);
        lb[i] = (unsigned char)b;
        atomicAdd(&lh[b], 1);
    }
    __syncthreads();
    for (int i = threadIdx.x; i < NCB; i += 256)
        if (lh[i]) lseg[i] = atomicAdd(&gcur[i], lh[i]);
    __syncthreads();
    for (int i = threadIdx.x; i < cnt; i += 256) {
        int b = lb[i];
        int r = atomicAdd(&lcur[b], 1);
        stage[lseg[b] + r] = lv[i];
    }
}

// Per-bucket degree -> dis = rsqrt(deg+1)
__global__ __launch_bounds__(1024) void k_deg(
    const unsigned* __restrict__ stage, const int* __restrict__ gbase,
    float* __restrict__ dis, int n) {
    __shared__ int lh[1024];
    int t = threadIdx.x, B = blockIdx.x;
    lh[t] = 0;
    __syncthreads();
    int s0 = gbase[B], s1 = gbase[B + 1];
    for (int i = s0 + t; i < s1; i += 1024)
        atomicAdd(&lh[stage[i] >> 18], 1);
    __syncthreads();
    int node = B * 1024 + t;
    if (node < n) dis[node] = rsqrtf((float)(lh[t] + 1));
}

// Layer 1 matmul: hw = x @ W1  (x:[N,256], W1:[256,16])
__global__ __launch_bounds__(256) void k_mm1(
    const float* __restrict__ x, const float* __restrict__ W,
    float* __restrict__ hw, int n) {
    __shared__ float Wl[256 * 16];
    int t = threadIdx.x;
#pragma unroll
    for (int i = 0; i < 4; ++i)
        ((float4*)Wl)[t + i * 256] = ((const float4*)W)[t + i * 256];
    __syncthreads();

    int node = blockIdx.x * 256 + t;
    if (node >= n) return;

    const float4* xr = (const float4*)(x + (long)node * 256);
    float acc[16];
#pragma unroll
    for (int o = 0; o < 16; ++o) acc[o] = 0.f;

#pragma unroll 8
    for (int kk = 0; kk < 64; ++kk) {
        float4 xv = xr[kk];
#pragma unroll
        for (int q = 0; q < 4; ++q) {
            float xs = (q == 0) ? xv.x : (q == 1) ? xv.y : (q == 2) ? xv.z : xv.w;
            const float4* wr = (const float4*)&Wl[(kk * 4 + q) * 16];
#pragma unroll
            for (int oo = 0; oo < 4; ++oo) {
                float4 wv = wr[oo];
                acc[oo * 4 + 0] = fmaf(xs, wv.x, acc[oo * 4 + 0]);
                acc[oo * 4 + 1] = fmaf(xs, wv.y, acc[oo * 4 + 1]);
                acc[oo * 4 + 2] = fmaf(xs, wv.z, acc[oo * 4 + 2]);
                acc[oo * 4 + 3] = fmaf(xs, wv.w, acc[oo * 4 + 3]);
            }
        }
    }
    float4* hwo = (float4*)(hw + (long)node * 16);
#pragma unroll
    for (int oo = 0; oo < 4; ++oo)
        hwo[oo] = make_float4(acc[oo * 4], acc[oo * 4 + 1], acc[oo * 4 + 2], acc[oo * 4 + 3]);
}

// 16x16 matmul: hw = h @ W (h already relu'd by gather epilogue)
__global__ __launch_bounds__(256) void k_mm2(
    const float* __restrict__ h, const float* __restrict__ W,
    float* __restrict__ hw, int n) {
    __shared__ float Wl[256];
    if (threadIdx.x < 64) ((float4*)Wl)[threadIdx.x] = ((const float4*)W)[threadIdx.x];
    __syncthreads();
    int node = blockIdx.x * 256 + threadIdx.x;
    if (node >= n) return;
    float hv[16];
    const float4* hr = (const float4*)(h + (long)node * 16);
#pragma unroll
    for (int i = 0; i < 4; ++i) {
        float4 v = hr[i];
        hv[i * 4 + 0] = v.x; hv[i * 4 + 1] = v.y; hv[i * 4 + 2] = v.z; hv[i * 4 + 3] = v.w;
    }
    float acc[16];
#pragma unroll
    for (int o = 0; o < 16; ++o) acc[o] = 0.f;
#pragma unroll
    for (int k = 0; k < 16; ++k) {
        float xs = hv[k];
#pragma unroll
        for (int o = 0; o < 16; ++o) acc[o] = fmaf(xs, Wl[k * 16 + o], acc[o]);
    }
    float4* hwo = (float4*)(hw + (long)node * 16);
#pragma unroll
    for (int oo = 0; oo < 4; ++oo)
        hwo[oo] = make_float4(acc[oo * 4], acc[oo * 4 + 1], acc[oo * 4 + 2], acc[oo * 4 + 3]);
}

// 16x1 matmul: hw3 = h @ W3
__global__ __launch_bounds__(256) void k_mm3(
    const float* __restrict__ h, const float* __restrict__ W,
    float* __restrict__ hw3, int n) {
    int node = blockIdx.x * 256 + threadIdx.x;
    if (node >= n) return;
    const float4* hr = (const float4*)(h + (long)node * 16);
    float acc = 0.f;
#pragma unroll
    for (int i = 0; i < 4; ++i) {
        float4 v = hr[i];
        acc = fmaf(v.x, W[i * 4 + 0], acc);
        acc = fmaf(v.y, W[i * 4 + 1], acc);
        acc = fmaf(v.z, W[i * 4 + 2], acc);
        acc = fmaf(v.w, W[i * 4 + 3], acc);
    }
    hw3[node] = acc;
}

// Gather-aggregate, 16 ch, one block per coarse bucket. LDS accumulator
// agg[1024][16]; edges processed in parallel (16-lane ch groups x 4-edge ILP)
// with LDS float atomics; epilogue fuses self-loop + bias + optional relu.
template <int RELU>
__global__ __launch_bounds__(1024) void k_gath16(
    const unsigned* __restrict__ stage, const int* __restrict__ gbase,
    const float* __restrict__ dis, const float* __restrict__ hw,
    const float* __restrict__ bias, float* __restrict__ aggout, int n) {
    __shared__ float agg[1024 * 16];
    int t = threadIdx.x, B = blockIdx.x;
#pragma unroll
    for (int i = 0; i < 16; ++i) agg[t + i * 1024] = 0.f;
    __syncthreads();
    int s0 = gbase[B], s1 = gbase[B + 1];
    int g = t >> 4, c = t & 15;
    for (int base = s0 + g * 4; base < s1; base += 64 * 4) {
        if (base + 4 <= s1) {
            unsigned e0 = stage[base], e1 = stage[base + 1];
            unsigned e2 = stage[base + 2], e3 = stage[base + 3];
            int sA = e0 & 0x3FFFF, sB = e1 & 0x3FFFF, sC = e2 & 0x3FFFF, sD = e3 & 0x3FFFF;
            float w0 = dis[sA], w1 = dis[sB], w2 = dis[sC], w3 = dis[sD];
            float h0 = hw[(long)sA * 16 + c], h1 = hw[(long)sB * 16 + c];
            float h2 = hw[(long)sC * 16 + c], h3 = hw[(long)sD * 16 + c];
            atomicAdd(&agg[(e0 >> 18) * 16 + c], w0 * h0);
            atomicAdd(&agg[(e1 >> 18) * 16 + c], w1 * h1);
            atomicAdd(&agg[(e2 >> 18) * 16 + c], w2 * h2);
            atomicAdd(&agg[(e3 >> 18) * 16 + c], w3 * h3);
        } else {
            for (int k = base; k < s1; ++k) {
                unsigned e0 = stage[k];
                int sA = e0 & 0x3FFFF;
                atomicAdd(&agg[(e0 >> 18) * 16 + c], dis[sA] * hw[(long)sA * 16 + c]);
            }
        }
    }
    __syncthreads();
    int nodes = min(1024, n - B * 1024);
    for (int i = (t >> 4); i < nodes; i += 64) {
        long node = (long)B * 1024 + i;
        float dv = dis[node];
        float r = fmaf(dv, fmaf(dv, hw[node * 16 + c], agg[i * 16 + c]), bias[c]);
        if (RELU) r = fmaxf(r, 0.f);
        aggout[node * 16 + c] = r;
    }
}

// Gather-aggregate, 1 ch, one block per coarse bucket.
__global__ __launch_bounds__(1024) void k_gath1(
    const unsigned* __restrict__ stage, const int* __restrict__ gbase,
    const float* __restrict__ dis, const float* __restrict__ hw3,
    const float* __restrict__ b3, float* __restrict__ out, int n) {
    __shared__ float agg[1024];
    int t = threadIdx.x, B = blockIdx.x;
    agg[t] = 0.f;
    __syncthreads();
    int s0 = gbase[B], s1 = gbase[B + 1];
    for (int base = s0 + t * 4; base < s1; base += 1024 * 4) {
        if (base + 4 <= s1) {
            unsigned e0 = stage[base], e1 = stage[base + 1];
            unsigned e2 = stage[base + 2], e3 = stage[base + 3];
            int sA = e0 & 0x3FFFF, sB = e1 & 0x3FFFF, sC = e2 & 0x3FFFF, sD = e3 & 0x3FFFF;
            float p0 = dis[sA] * hw3[sA], p1 = dis[sB] * hw3[sB];
            float p2 = dis[sC] * hw3[sC], p3 = dis[sD] * hw3[sD];
            atomicAdd(&agg[e0 >> 18], p0);
            atomicAdd(&agg[e1 >> 18], p1);
            atomicAdd(&agg[e2 >> 18], p2);
            atomicAdd(&agg[e3 >> 18], p3);
        } else {
            for (int k = base; k < s1; ++k) {
                unsigned e0 = stage[k];
                int sA = e0 & 0x3FFFF;
                atomicAdd(&agg[e0 >> 18], dis[sA] * hw3[sA]);
            }
        }
    }
    __syncthreads();
    int node = B * 1024 + t;
    if (node < n) {
        float dv = dis[node];
        out[node] = fmaf(dv, fmaf(dv, hw3[node], agg[t]), b3[0]);
    }
}

extern "C" void kernel_launch(void* const* d_in, const int* in_sizes, int n_in,
                              void* d_out, int out_size, void* d_ws, size_t ws_size,
                              hipStream_t stream) {
    const float* x  = (const float*)d_in[0];
    const int*   ew = (const int*)d_in[1];
    const float* W1 = (const float*)d_in[2];
    const float* b1 = (const float*)d_in[3];
    const float* W2 = (const float*)d_in[4];
    const float* b2 = (const float*)d_in[5];
    const float* W3 = (const float*)d_in[6];
    const float* b3 = (const float*)d_in[7];
    float* out = (float*)d_out;

    // Workspace (4-byte words): stage 25.6MB | counts/gbase/gcur/flag | dis | bufA | bufB  (~52 MB)
    unsigned* stage  = (unsigned*)d_ws;            // 6,400,000
    int*      counts = (int*)(stage + EE);         // 256
    int*      gbase  = counts + 256;               // 256 (NCB+1 used)
    int*      gcur   = gbase + 256;                // 256
    int*      flag   = gcur + 256;                 // 16
    float*    dis    = (float*)(flag + 16);        // 200,704
    float*    bufA   = dis + 200704;               // 3,276,800 (hw / hw3)
    float*    bufB   = bufA + 3276800;             // 3,276,800 (h)

    const int n = NN;
    const long e = EE;
    int nb = (n + 255) / 256;  // 782

    k_detect<<<1, 256, 0, stream>>>(ew, flag);
    hipMemsetAsync(counts, 0, 256 * sizeof(int), stream);

    // Partition build: hist -> scan -> tile-segmented scatter -> degrees
    k_histA<<<NTILE, 256, 0, stream>>>(ew, flag, counts, e);
    k_scanA<<<1, 256, 0, stream>>>(counts, gbase, gcur);
    k_passA<<<NTILE, 256, 0, stream>>>(ew, flag, gcur, stage, e);
    k_deg<<<NCB, 1024, 0, stream>>>(stage, gbase, dis, n);

    // Layer 1
    k_mm1<<<nb, 256, 0, stream>>>(x, W1, bufA, n);
    k_gath16<1><<<NCB, 1024, 0, stream>>>(stage, gbase, dis, bufA, b1, bufB, n);
    // Layer 2
    k_mm2<<<nb, 256, 0, stream>>>(bufB, W2, bufA, n);
    k_gath16<1><<<NCB, 1024, 0, stream>>>(stage, gbase, dis, bufA, b2, bufB, n);
    // Layer 3
    k_mm3<<<nb, 256, 0, stream>>>(bufB, W3, bufA, n);
    k_gath1<<<NCB, 1024, 0, stream>>>(stage, gbase, dis, bufA, b3, out, n);
}

// Round 5
// 463.220 us; speedup vs baseline: 3.4734x; 3.4734x over previous
//
#include <hip/hip_runtime.h>

#define NN 200000
#define EE 6400000L
#define NCB 196          // coarse buckets of 1024 nodes
#define TILE 8192
#define NTILE 782        // ceil(6400000/8192)

// ---------------------------------------------------------------------------
// Edge-index dtype hedge (int64 vs int32): if int64 with values < 2^31, every
// odd 32-bit word is zero. flag=1 -> int64 (word idx = elem<<1), 0 -> int32.
// ---------------------------------------------------------------------------
__global__ void k_detect(const int* __restrict__ w, int* __restrict__ flag) {
    __shared__ int any;
    if (threadIdx.x == 0) any = 0;
    __syncthreads();
    int found = 0;
    for (int i = threadIdx.x; i < 8192; i += 256)
        if (w[2 * i + 1] != 0) found = 1;
    if (found) atomicOr(&any, 1);
    __syncthreads();
    if (threadIdx.x == 0) flag[0] = any ? 0 : 1;
}

// LDS-aggregated histogram of coarse bucket (d>>10)
__global__ __launch_bounds__(256) void k_histA(
    const int* __restrict__ ew, const int* __restrict__ flag,
    int* __restrict__ counts, long e) {
    __shared__ int lh[NCB];
    for (int i = threadIdx.x; i < NCB; i += 256) lh[i] = 0;
    __syncthreads();
    long t0 = (long)blockIdx.x * TILE;
    int cnt = (int)min((long)TILE, e - t0);
    int shift = *flag;
    for (int i = threadIdx.x; i < cnt; i += 256) {
        int d = ew[(EE + t0 + i) << shift];
        atomicAdd(&lh[d >> 10], 1);
    }
    __syncthreads();
    for (int i = threadIdx.x; i < NCB; i += 256)
        if (lh[i]) atomicAdd(&counts[i], lh[i]);
}

// Exclusive scan of counts[NCB] -> gbase[NCB+1]; gcur = gbase
__global__ __launch_bounds__(256) void k_scanA(
    const int* __restrict__ counts, int* __restrict__ gbase, int* __restrict__ gcur) {
    __shared__ int ws[4];
    int t = threadIdx.x;
    int v = (t < NCB) ? counts[t] : 0;
    int lane = t & 63, w = t >> 6;
    int s = v;
#pragma unroll
    for (int o = 1; o < 64; o <<= 1) {
        int u = __shfl_up(s, o, 64);
        if (lane >= o) s += u;
    }
    if (lane == 63) ws[w] = s;
    __syncthreads();
    int add = 0;
    for (int k = 0; k < w; ++k) add += ws[k];
    int excl = s - v + add;
    if (t <= NCB) gbase[t] = excl;   // t==NCB gets the grand total
    if (t < NCB) gcur[t] = excl;
}

// Partition into coarse buckets with tile-exclusive segments.
// stage entry: src[17:0] | local_dst[27:18]
__global__ __launch_bounds__(256) void k_passA(
    const int* __restrict__ ew, const int* __restrict__ flag,
    int* __restrict__ gcur, unsigned* __restrict__ stage, long e) {
    __shared__ unsigned lv[TILE];
    __shared__ unsigned char lb[TILE];
    __shared__ int lh[NCB], lseg[NCB], lcur[NCB];
    for (int i = threadIdx.x; i < NCB; i += 256) { lh[i] = 0; lcur[i] = 0; }
    __syncthreads();
    long t0 = (long)blockIdx.x * TILE;
    int cnt = (int)min((long)TILE, e - t0);
    int shift = *flag;
    for (int i = threadIdx.x; i < cnt; i += 256) {
        int s = ew[(t0 + i) << shift];
        int d = ew[(EE + t0 + i) << shift];
        int b = d >> 10;
        lv[i] = (unsigned)s | ((unsigned)(d & 1023) << 18);
        lb[i] = (unsigned char)b;
        atomicAdd(&lh[b], 1);
    }
    __syncthreads();
    for (int i = threadIdx.x; i < NCB; i += 256)
        if (lh[i]) lseg[i] = atomicAdd(&gcur[i], lh[i]);
    __syncthreads();
    for (int i = threadIdx.x; i < cnt; i += 256) {
        int b = lb[i];
        int r = atomicAdd(&lcur[b], 1);
        stage[lseg[b] + r] = lv[i];
    }
}

// Per-bucket counting sort: stage (bucket-grouped) -> csr (node-grouped, src only).
// Also emits offn/degn/dis. All scattered writes stay in the block-owned segment.
__global__ __launch_bounds__(1024) void k_sortB(
    const unsigned* __restrict__ stage, const int* __restrict__ gbase,
    float* __restrict__ dis, int* __restrict__ offn, int* __restrict__ degn,
    unsigned* __restrict__ csr, int n) {
    __shared__ int cnt[1024];
    __shared__ int cur[1024];
    __shared__ int wsum[16];
    int t = threadIdx.x, B = blockIdx.x;
    cnt[t] = 0;
    __syncthreads();
    int s0 = gbase[B], s1 = gbase[B + 1];
    for (int i = s0 + t; i < s1; i += 1024)
        atomicAdd(&cnt[stage[i] >> 18], 1);
    __syncthreads();
    int c = cnt[t];
    int lane = t & 63, w = t >> 6;
    int s = c;
#pragma unroll
    for (int o = 1; o < 64; o <<= 1) {
        int u = __shfl_up(s, o, 64);
        if (lane >= o) s += u;
    }
    if (lane == 63) wsum[w] = s;
    __syncthreads();
    int add = 0;
    for (int k = 0; k < w; ++k) add += wsum[k];
    int excl = s - c + add;
    cur[t] = excl;
    int node = B * 1024 + t;
    if (node < n) {
        offn[node] = s0 + excl;
        degn[node] = c;
        dis[node] = rsqrtf((float)(c + 1));
    }
    __syncthreads();
    for (int i = s0 + t; i < s1; i += 1024) {
        unsigned v = stage[i];
        int pos = s0 + atomicAdd(&cur[v >> 18], 1);
        csr[pos] = v & 0x3FFFF;
    }
}

// Layer 1 matmul: hws = dis ⊙ (x @ W1)  (x:[N,256], W1:[256,16])
__global__ __launch_bounds__(256) void k_mm1(
    const float* __restrict__ x, const float* __restrict__ W,
    const float* __restrict__ dis, float* __restrict__ hws, int n) {
    __shared__ float Wl[256 * 16];
    int t = threadIdx.x;
#pragma unroll
    for (int i = 0; i < 4; ++i)
        ((float4*)Wl)[t + i * 256] = ((const float4*)W)[t + i * 256];
    __syncthreads();

    int node = blockIdx.x * 256 + t;
    if (node >= n) return;

    const float4* xr = (const float4*)(x + (long)node * 256);
    float acc[16];
#pragma unroll
    for (int o = 0; o < 16; ++o) acc[o] = 0.f;

#pragma unroll 8
    for (int kk = 0; kk < 64; ++kk) {
        float4 xv = xr[kk];
#pragma unroll
        for (int q = 0; q < 4; ++q) {
            float xs = (q == 0) ? xv.x : (q == 1) ? xv.y : (q == 2) ? xv.z : xv.w;
            const float4* wr = (const float4*)&Wl[(kk * 4 + q) * 16];
#pragma unroll
            for (int oo = 0; oo < 4; ++oo) {
                float4 wv = wr[oo];
                acc[oo * 4 + 0] = fmaf(xs, wv.x, acc[oo * 4 + 0]);
                acc[oo * 4 + 1] = fmaf(xs, wv.y, acc[oo * 4 + 1]);
                acc[oo * 4 + 2] = fmaf(xs, wv.z, acc[oo * 4 + 2]);
                acc[oo * 4 + 3] = fmaf(xs, wv.w, acc[oo * 4 + 3]);
            }
        }
    }
    float dv = dis[node];
    float4* hwo = (float4*)(hws + (long)node * 16);
#pragma unroll
    for (int oo = 0; oo < 4; ++oo)
        hwo[oo] = make_float4(acc[oo * 4] * dv, acc[oo * 4 + 1] * dv,
                              acc[oo * 4 + 2] * dv, acc[oo * 4 + 3] * dv);
}

// 16x16 matmul: hws = dis ⊙ (h @ W)
__global__ __launch_bounds__(256) void k_mm2(
    const float* __restrict__ h, const float* __restrict__ W,
    const float* __restrict__ dis, float* __restrict__ hws, int n) {
    __shared__ float Wl[256];
    if (threadIdx.x < 64) ((float4*)Wl)[threadIdx.x] = ((const float4*)W)[threadIdx.x];
    __syncthreads();
    int node = blockIdx.x * 256 + threadIdx.x;
    if (node >= n) return;
    float hv[16];
    const float4* hr = (const float4*)(h + (long)node * 16);
#pragma unroll
    for (int i = 0; i < 4; ++i) {
        float4 v = hr[i];
        hv[i * 4 + 0] = v.x; hv[i * 4 + 1] = v.y; hv[i * 4 + 2] = v.z; hv[i * 4 + 3] = v.w;
    }
    float acc[16];
#pragma unroll
    for (int o = 0; o < 16; ++o) acc[o] = 0.f;
#pragma unroll
    for (int k = 0; k < 16; ++k) {
        float xs = hv[k];
#pragma unroll
        for (int o = 0; o < 16; ++o) acc[o] = fmaf(xs, Wl[k * 16 + o], acc[o]);
    }
    float dv = dis[node];
    float4* hwo = (float4*)(hws + (long)node * 16);
#pragma unroll
    for (int oo = 0; oo < 4; ++oo)
        hwo[oo] = make_float4(acc[oo * 4] * dv, acc[oo * 4 + 1] * dv,
                              acc[oo * 4 + 2] * dv, acc[oo * 4 + 3] * dv);
}

// 16x1 matmul: hws3 = dis ⊙ (h @ W3)
__global__ __launch_bounds__(256) void k_mm3(
    const float* __restrict__ h, const float* __restrict__ W,
    const float* __restrict__ dis, float* __restrict__ hws3, int n) {
    int node = blockIdx.x * 256 + threadIdx.x;
    if (node >= n) return;
    const float4* hr = (const float4*)(h + (long)node * 16);
    float acc = 0.f;
#pragma unroll
    for (int i = 0; i < 4; ++i) {
        float4 v = hr[i];
        acc = fmaf(v.x, W[i * 4 + 0], acc);
        acc = fmaf(v.y, W[i * 4 + 1], acc);
        acc = fmaf(v.z, W[i * 4 + 2], acc);
        acc = fmaf(v.w, W[i * 4 + 3], acc);
    }
    hws3[node] = acc * dis[node];
}

// Gather-aggregate, 16 channels. Block = 16 nodes x 16 lanes(=channels).
// h[i,ch] = relu?( b[ch] + dv*( sum_e hws[src_e,ch] + hws[i,ch] ) )
template <int RELU>
__global__ __launch_bounds__(256) void k_g16(
    const int* __restrict__ offn, const int* __restrict__ degn,
    const unsigned* __restrict__ csr, const float* __restrict__ dis,
    const float* __restrict__ hws, const float* __restrict__ b,
    float* __restrict__ h, int n) {
    int t = threadIdx.x;
    int node = blockIdx.x * 16 + (t >> 4);
    int ch = t & 15;
    if (node >= n) return;
    int s0 = offn[node];
    int dg = degn[node];
    float a0 = 0.f, a1 = 0.f, a2 = 0.f, a3 = 0.f;
    int k = 0;
    for (; k + 3 < dg; k += 4) {
        unsigned e0 = csr[s0 + k], e1 = csr[s0 + k + 1];
        unsigned e2 = csr[s0 + k + 2], e3 = csr[s0 + k + 3];
        a0 += hws[(long)e0 * 16 + ch];
        a1 += hws[(long)e1 * 16 + ch];
        a2 += hws[(long)e2 * 16 + ch];
        a3 += hws[(long)e3 * 16 + ch];
    }
    for (; k < dg; ++k)
        a0 += hws[(long)csr[s0 + k] * 16 + ch];
    float dv = dis[node];
    float sum = (a0 + a1) + (a2 + a3) + hws[(long)node * 16 + ch];
    float r = fmaf(dv, sum, b[ch]);
    if (RELU) r = fmaxf(r, 0.f);
    h[(long)node * 16 + ch] = r;
}

// Gather-aggregate, 1 channel from the 800KB pre-scaled table (L2-resident).
__global__ __launch_bounds__(256) void k_g1(
    const int* __restrict__ offn, const int* __restrict__ degn,
    const unsigned* __restrict__ csr, const float* __restrict__ dis,
    const float* __restrict__ hws3, const float* __restrict__ b,
    float* __restrict__ out, int n) {
    int t = threadIdx.x;
    int node = blockIdx.x * 16 + (t >> 4);
    int ln = t & 15;
    if (node >= n) return;
    int s0 = offn[node], dg = degn[node];
    float acc = 0.f;
    for (int k = ln; k < dg; k += 16)
        acc += hws3[csr[s0 + k]];
#pragma unroll
    for (int o = 8; o >= 1; o >>= 1) acc += __shfl_down(acc, o, 16);
    if (ln == 0)
        out[node] = fmaf(dis[node], acc + hws3[node], b[0]);
}

extern "C" void kernel_launch(void* const* d_in, const int* in_sizes, int n_in,
                              void* d_out, int out_size, void* d_ws, size_t ws_size,
                              hipStream_t stream) {
    const float* x  = (const float*)d_in[0];
    const int*   ew = (const int*)d_in[1];
    const float* W1 = (const float*)d_in[2];
    const float* b1 = (const float*)d_in[3];
    const float* W2 = (const float*)d_in[4];
    const float* b2 = (const float*)d_in[5];
    const float* W3 = (const float*)d_in[6];
    const float* b3 = (const float*)d_in[7];
    float* out = (float*)d_out;

    // Workspace (4-byte words), ~54 MB. stage ALIASES bufA∪bufB (dead before mm1).
    unsigned* csr    = (unsigned*)d_ws;            // 6,400,000
    int*      counts = (int*)(csr + EE);           // 256
    int*      gbase  = counts + 256;               // 256 (NCB+1 used)
    int*      gcur   = gbase + 256;                // 256
    int*      flag   = gcur + 256;                 // 16
    int*      offn   = flag + 16;                  // 200,704
    int*      degn   = offn + 200704;              // 200,704
    float*    dis    = (float*)(degn + 200704);    // 200,704
    float*    bufA   = dis + 200704;               // 3,276,800 (hws / hws3)
    float*    bufB   = bufA + 3276800;             // 3,276,800 (h)
    unsigned* stage  = (unsigned*)bufA;            // 6,400,000 (aliases bufA+bufB)

    const int n = NN;
    const long e = EE;
    int nb = (n + 255) / 256;   // 782
    int gb = (n + 15) / 16;     // 12500

    k_detect<<<1, 256, 0, stream>>>(ew, flag);
    hipMemsetAsync(counts, 0, 256 * sizeof(int), stream);

    // Partition build: hist -> scan -> tile-segmented scatter -> per-bucket sort
    k_histA<<<NTILE, 256, 0, stream>>>(ew, flag, counts, e);
    k_scanA<<<1, 256, 0, stream>>>(counts, gbase, gcur);
    k_passA<<<NTILE, 256, 0, stream>>>(ew, flag, gcur, stage, e);
    k_sortB<<<NCB, 1024, 0, stream>>>(stage, gbase, dis, offn, degn, csr, n);

    // Layer 1
    k_mm1<<<nb, 256, 0, stream>>>(x, W1, dis, bufA, n);
    k_g16<1><<<gb, 256, 0, stream>>>(offn, degn, csr, dis, bufA, b1, bufB, n);
    // Layer 2
    k_mm2<<<nb, 256, 0, stream>>>(bufB, W2, dis, bufA, n);
    k_g16<1><<<gb, 256, 0, stream>>>(offn, degn, csr, dis, bufA, b2, bufB, n);
    // Layer 3
    k_mm3<<<nb, 256, 0, stream>>>(bufB, W3, dis, bufA, n);
    k_g1<<<gb, 256, 0, stream>>>(offn, degn, csr, dis, bufA, b3, out, n);
}